// Round 15
// baseline (210.863 us; speedup 1.0000x reference)
//
#include <hip/hip_runtime.h>

typedef unsigned short u16;
typedef __attribute__((ext_vector_type(8))) short bf16x8;
typedef __attribute__((ext_vector_type(4))) short s16x4;
typedef __attribute__((ext_vector_type(4))) float f32x4;

#define GLDS(g, l) __builtin_amdgcn_global_load_lds( \
    (const __attribute__((address_space(1))) unsigned int*)(g), \
    (__attribute__((address_space(3))) unsigned int*)(l), 16, 0, 0)

__device__ __forceinline__ u16 f2b(float f) {
  unsigned int x = __float_as_uint(f);
  return (u16)((x + 0x7fffu + ((x >> 16) & 1u)) >> 16);
}
__device__ __forceinline__ bf16x8 cvt8(float4 a, float4 b) {
  bf16x8 r;
  r[0] = (short)f2b(a.x); r[1] = (short)f2b(a.y);
  r[2] = (short)f2b(a.z); r[3] = (short)f2b(a.w);
  r[4] = (short)f2b(b.x); r[5] = (short)f2b(b.y);
  r[6] = (short)f2b(b.z); r[7] = (short)f2b(b.w);
  return r;
}

// ---- all 4 weight transposes in one launch: Wt[n][k] = bf16(W[k][n]) ----
__global__ __launch_bounds__(256) void transpose_w4(
    const float* __restrict__ W0, const float* __restrict__ W1,
    const float* __restrict__ W2, const float* __restrict__ W3,
    u16* __restrict__ D0, u16* __restrict__ D1,
    u16* __restrict__ D2, u16* __restrict__ D3) {
  const int z = blockIdx.z;
  const float* W = (z == 0) ? W0 : (z == 1) ? W1 : (z == 2) ? W2 : W3;
  u16* Wt = (z == 0) ? D0 : (z == 1) ? D1 : (z == 2) ? D2 : D3;
  __shared__ u16 tile[32][33];
  const int tx = threadIdx.x & 31, ty = threadIdx.x >> 5;
  const int r0 = blockIdx.y * 32, c0 = blockIdx.x * 32;
#pragma unroll
  for (int i = 0; i < 32; i += 8)
    tile[ty + i][tx] = f2b(W[(r0 + ty + i) * 1024 + c0 + tx]);
  __syncthreads();
#pragma unroll
  for (int i = 0; i < 32; i += 8)
    Wt[(c0 + ty + i) * 1024 + r0 + tx] = tile[tx][ty + i];
}

// ------- FUSED Q + K + V projection GEMM: one launch, grid (64, 24) -------
// All A-operands f32, reg-staged -> bf16 LDS (RNE f2b == the old cvt kernel,
// so Q/K/V values are bit-identical to the r14 build; cvt kernel deleted).
// y<8:  A = x,  Bt = Wqt  -> Qb row-major.
// y in [8,24): A = xo, Bt = Wkvt rows (y-8)*128; y-8<8 -> K row-major to Kb;
//              else V^T scatter to Vtb[(b,h),dd,n].
// 128x128 tile, BK=32, 4 waves, 16x16x32 MFMA, double-buffered prefetch.
__global__ __launch_bounds__(256) void gemm_fused(
    const float* __restrict__ Ax, const float* __restrict__ Axo,
    const u16* __restrict__ Wqt, const u16* __restrict__ Wkvt,
    u16* __restrict__ Qb, u16* __restrict__ Kb, u16* __restrict__ Vtb) {
  __shared__ u16 As[2][128 * 32];
  __shared__ u16 Bs[2][128 * 32];
  const int t = threadIdx.x;
  const int wave = t >> 6, lane = t & 63;
  const int g = lane >> 4, a15 = lane & 15;
  const int wr = wave >> 1, wc = wave & 1;
  const int row0 = t >> 2;            // 0..63
  const int col0 = (t & 3) * 8;       // 0,8,16,24
  const int y = blockIdx.y;
  const bool qpart = (y < 8);
  const float* A = qpart ? Ax : Axo;
  const u16* Bt = qpart ? Wqt : Wkvt;
  const int yb = qpart ? y : (y - 8);
  const int abase = (blockIdx.x * 128 + row0) * 1024 + col0;
  const int bbase = (yb * 128 + row0) * 1024 + col0;

  f32x4 acc[4][4] = {};

  // ---- prologue: stage K-step 0 into buffer 0 ----
  GLDS(Bt + bbase, &Bs[0][wave * 512]);
  GLDS(Bt + bbase + 64 * 1024, &Bs[0][2048 + wave * 512]);
  {
    const float* Ag = A + abase;
    const float4 x0 = *(const float4*)(Ag);
    const float4 x1 = *(const float4*)(Ag + 4);
    const float4 y0 = *(const float4*)(Ag + 64 * 1024);
    const float4 y1 = *(const float4*)(Ag + 64 * 1024 + 4);
    *(bf16x8*)&As[0][row0 * 32 + col0] = cvt8(x0, x1);
    *(bf16x8*)&As[0][(row0 + 64) * 32 + col0] = cvt8(y0, y1);
  }
  __syncthreads();

  for (int ki = 0; ki < 32; ++ki) {
    const int cur = ki & 1, nxt = cur ^ 1;
    const int ktn = (ki + 1) * 32;
    const bool pf = ki < 31;
    float4 x0, x1, y0, y1;
    if (pf) {
      GLDS(Bt + bbase + ktn, &Bs[nxt][wave * 512]);
      GLDS(Bt + bbase + 64 * 1024 + ktn, &Bs[nxt][2048 + wave * 512]);
      const float* Ag = A + abase + ktn;
      x0 = *(const float4*)(Ag);
      x1 = *(const float4*)(Ag + 4);
      y0 = *(const float4*)(Ag + 64 * 1024);
      y1 = *(const float4*)(Ag + 64 * 1024 + 4);
    }
    bf16x8 af[4], bfr[4];
#pragma unroll
    for (int mi = 0; mi < 4; ++mi)
      af[mi] = *(const bf16x8*)&As[cur][(wr * 64 + mi * 16 + a15) * 32 + g * 8];
#pragma unroll
    for (int ni = 0; ni < 4; ++ni)
      bfr[ni] = *(const bf16x8*)&Bs[cur][(wc * 64 + ni * 16 + a15) * 32 + g * 8];
#pragma unroll
    for (int mi = 0; mi < 4; ++mi)
#pragma unroll
      for (int ni = 0; ni < 4; ++ni)
        acc[mi][ni] = __builtin_amdgcn_mfma_f32_16x16x32_bf16(af[mi], bfr[ni], acc[mi][ni], 0, 0, 0);
    if (pf) {
      *(bf16x8*)&As[nxt][row0 * 32 + col0] = cvt8(x0, x1);
      *(bf16x8*)&As[nxt][(row0 + 64) * 32 + col0] = cvt8(y0, y1);
    }
    __syncthreads();
  }

  const int crow = blockIdx.x * 128 + wr * 64 + g * 4;
  const int ccol = yb * 128 + wc * 64 + a15;
  if (qpart) {
#pragma unroll
    for (int mi = 0; mi < 4; ++mi)
#pragma unroll
      for (int ni = 0; ni < 4; ++ni)
#pragma unroll
        for (int r = 0; r < 4; ++r)
          Qb[(crow + mi * 16 + r) * 1024 + ccol + ni * 16] = f2b(acc[mi][ni][r]);
  } else if (yb < 8) {
#pragma unroll
    for (int mi = 0; mi < 4; ++mi)
#pragma unroll
      for (int ni = 0; ni < 4; ++ni)
#pragma unroll
        for (int r = 0; r < 4; ++r)
          Kb[(crow + mi * 16 + r) * 1024 + ccol + ni * 16] = f2b(acc[mi][ni][r]);
  } else {
    // V part: Vt[((b*16+h)*64 + dd)*2048 + n], col c = ccol - 1024
#pragma unroll
    for (int mi = 0; mi < 4; ++mi) {
      const int n = crow + mi * 16;
      const int bq = n >> 11;
      const int nl = n & 2047;
#pragma unroll
      for (int ni = 0; ni < 4; ++ni) {
        const int c = ccol + ni * 16 - 1024;
        s16x4 v4;
        v4[0] = (short)f2b(acc[mi][ni][0]);
        v4[1] = (short)f2b(acc[mi][ni][1]);
        v4[2] = (short)f2b(acc[mi][ni][2]);
        v4[3] = (short)f2b(acc[mi][ni][3]);
        *(s16x4*)&Vtb[(((bq << 4) + (c >> 6)) * 64 + (c & 63)) * 2048 + nl] = v4;
      }
    }
  }
}

// ---------------- out-GEMM: C(f32) = A(bf16) * Bt^T, same 128^2 dbuf core ----------------
__global__ __launch_bounds__(256) void gemm_out(const u16* __restrict__ A,
                                                const u16* __restrict__ Bt,
                                                float* __restrict__ C) {
  __shared__ u16 As[2][128 * 32];
  __shared__ u16 Bs[2][128 * 32];
  const int t = threadIdx.x;
  const int wave = t >> 6, lane = t & 63;
  const int g = lane >> 4, a15 = lane & 15;
  const int wr = wave >> 1, wc = wave & 1;
  const int row0 = t >> 2;
  const int col0 = (t & 3) * 8;
  const int abase = (blockIdx.x * 128 + row0) * 1024 + col0;
  const int bbase = (blockIdx.y * 128 + row0) * 1024 + col0;

  f32x4 acc[4][4] = {};

  GLDS(A + abase, &As[0][wave * 512]);
  GLDS(A + abase + 64 * 1024, &As[0][2048 + wave * 512]);
  GLDS(Bt + bbase, &Bs[0][wave * 512]);
  GLDS(Bt + bbase + 64 * 1024, &Bs[0][2048 + wave * 512]);
  __syncthreads();

  for (int ki = 0; ki < 32; ++ki) {
    const int cur = ki & 1, nxt = cur ^ 1;
    const int ktn = (ki + 1) * 32;
    if (ki < 31) {
      GLDS(A + abase + ktn, &As[nxt][wave * 512]);
      GLDS(A + abase + 64 * 1024 + ktn, &As[nxt][2048 + wave * 512]);
      GLDS(Bt + bbase + ktn, &Bs[nxt][wave * 512]);
      GLDS(Bt + bbase + 64 * 1024 + ktn, &Bs[nxt][2048 + wave * 512]);
    }
    bf16x8 af[4], bfr[4];
#pragma unroll
    for (int mi = 0; mi < 4; ++mi)
      af[mi] = *(const bf16x8*)&As[cur][(wr * 64 + mi * 16 + a15) * 32 + g * 8];
#pragma unroll
    for (int ni = 0; ni < 4; ++ni)
      bfr[ni] = *(const bf16x8*)&Bs[cur][(wc * 64 + ni * 16 + a15) * 32 + g * 8];
#pragma unroll
    for (int mi = 0; mi < 4; ++mi)
#pragma unroll
      for (int ni = 0; ni < 4; ++ni)
        acc[mi][ni] = __builtin_amdgcn_mfma_f32_16x16x32_bf16(af[mi], bfr[ni], acc[mi][ni], 0, 0, 0);
    __syncthreads();
  }

  const int crow = blockIdx.x * 128 + wr * 64 + g * 4;
  const int ccol = blockIdx.y * 128 + wc * 64 + a15;
#pragma unroll
  for (int mi = 0; mi < 4; ++mi)
#pragma unroll
    for (int ni = 0; ni < 4; ++ni)
#pragma unroll
      for (int r = 0; r < 4; ++r)
        C[(crow + mi * 16 + r) * 1024 + ccol + ni * 16] = acc[mi][ni][r];
}

// ---------------- flash attention (r13 math, + setprio + lp hoist) ----------------
// 512-thread blocks (8 waves) sharing one K/V tile; grid 512 = 2 blocks/CU
// (16 waves/CU). Fixed-shift log2-domain softmax (exact by shift-invariance;
// EPS terms <=1e-8). O aliases Q (disjoint per-wave read/write regions).
// setprio(1) wraps the MFMA clusters (T5): the two independently-phased
// blocks/CU let the scheduler favor MFMA-entering waves.
__global__ __launch_bounds__(512) void attn_kernel(
    const u16* Q, const u16* __restrict__ K,
    const u16* __restrict__ Vt, const float* __restrict__ dec,
    u16* O) {
  const int f = blockIdx.x;
  const int bh = (f & 7) * 8 + ((f >> 3) & 7);   // 8 heads per XCD
  const int qx = f >> 6;                          // [0,8) q-tile of 256 rows
  const int b = bh >> 4, h = bh & 15;
  __shared__ u16 K_lds[2][64 * 64];
  __shared__ u16 V_lds[2][64 * 64];
  __shared__ __align__(16) u16 P_lds[8][32 * 72];
  __shared__ float l2p_lds[2048];

  const int wave = threadIdx.x >> 6, lane = threadIdx.x & 63;
  const int g = lane >> 4, a15 = lane & 15;
  u16* pl = &P_lds[wave][0];

  {
    const int i0 = threadIdx.x * 4;
    const float4 d0 = *(const float4*)&dec[b * 2048 + i0];
    float4 o0;
    o0.x = __log2f(fmaxf(1.f - d0.x, 1e-38f));
    o0.y = __log2f(fmaxf(1.f - d0.y, 1e-38f));
    o0.z = __log2f(fmaxf(1.f - d0.z, 1e-38f));
    o0.w = __log2f(fmaxf(1.f - d0.w, 1e-38f));
    *(float4*)&l2p_lds[i0] = o0;
  }

  bf16x8 qf[2][2];
  {
    const int qr = (b * 2048 + qx * 256 + wave * 32 + a15) * 1024 + h * 64 + g * 8;
#pragma unroll
    for (int qg = 0; qg < 2; ++qg) {
      qf[qg][0] = *(const bf16x8*)&Q[qr + qg * 16 * 1024];
      qf[qg][1] = *(const bf16x8*)&Q[qr + qg * 16 * 1024 + 32];
    }
  }

  const int srow = lane >> 3;
  const int swze = (((lane & 7) * 16) ^ (srow << 4)) >> 1;  // u16 elems
  const u16* Kg = K + ((size_t)(b * 2048 + wave * 8 + srow)) * 1024 + h * 64 + swze;
  const u16* Vg = Vt + ((size_t)(bh * 64 + wave * 8 + srow)) * 2048 + swze;
  u16* kdst[2] = {&K_lds[0][wave * 8 * 64], &K_lds[1][wave * 8 * 64]};
  u16* vdst[2] = {&V_lds[0][wave * 8 * 64], &V_lds[1][wave * 8 * 64]};

  GLDS(Kg, kdst[0]);
  GLDS(Vg, vdst[0]);
  __syncthreads();

  const float CSC = 0.125f * 1.44269504f;  // scale * log2(e)
  f32x4 acc[2][4] = {};
  f32x4 ls[2] = {};

  for (int it = 0; it < 32; ++it) {
    const int cur = it & 1, nxt = cur ^ 1;
    if (it < 31) {
      const int ktn = (it + 1) * 64;
      GLDS(Kg + (size_t)ktn * 1024, kdst[nxt]);
      GLDS(Vg + ktn, vdst[nxt]);
    }
    const int kt = it * 64;
    // lp hoisted once per tile (qg-invariant)
    float4 lp[4];
#pragma unroll
    for (int sub = 0; sub < 4; ++sub)
      lp[sub] = *(const float4*)&l2p_lds[kt + sub * 16 + g * 4];
    // --- S^T = K * Q^T : each K fragment read once, used by both q-groups ---
    f32x4 sf[2][4];
    __builtin_amdgcn_s_setprio(1);
#pragma unroll
    for (int sub = 0; sub < 4; ++sub) {
      const int krow = sub * 16 + a15;
      const char* kp = (const char*)&K_lds[cur][krow * 64];
      const int swz = (krow & 7) << 4;
      const bf16x8 k0 = *(const bf16x8*)(kp + ((g * 16) ^ swz));
      const bf16x8 k1 = *(const bf16x8*)(kp + ((g * 16 + 64) ^ swz));
#pragma unroll
      for (int qg = 0; qg < 2; ++qg) {
        f32x4 s = {0.f, 0.f, 0.f, 0.f};
        s = __builtin_amdgcn_mfma_f32_16x16x32_bf16(k0, qf[qg][0], s, 0, 0, 0);
        s = __builtin_amdgcn_mfma_f32_16x16x32_bf16(k1, qf[qg][1], s, 0, 0, 0);
        sf[qg][sub] = s;
      }
    }
    __builtin_amdgcn_s_setprio(0);
    // --- straight-line softmax both groups: e = exp2(s*CSC + l2p) ---
#pragma unroll
    for (int qg = 0; qg < 2; ++qg) {
#pragma unroll
      for (int sub = 0; sub < 4; ++sub) {
        const float e0 = __builtin_amdgcn_exp2f(fmaf(sf[qg][sub][0], CSC, lp[sub].x));
        const float e1 = __builtin_amdgcn_exp2f(fmaf(sf[qg][sub][1], CSC, lp[sub].y));
        const float e2 = __builtin_amdgcn_exp2f(fmaf(sf[qg][sub][2], CSC, lp[sub].z));
        const float e3 = __builtin_amdgcn_exp2f(fmaf(sf[qg][sub][3], CSC, lp[sub].w));
        ls[qg][0] += e0; ls[qg][1] += e1; ls[qg][2] += e2; ls[qg][3] += e3;
        unsigned int w0, w1;
        asm("v_cvt_pk_bf16_f32 %0, %1, %2" : "=v"(w0) : "v"(e0), "v"(e1));
        asm("v_cvt_pk_bf16_f32 %0, %1, %2" : "=v"(w1) : "v"(e2), "v"(e3));
        uint2 w; w.x = w0; w.y = w1;
        *(uint2*)&pl[(qg * 16 + a15) * 72 + sub * 16 + g * 4] = w;
      }
    }
    asm volatile("" ::: "memory");  // order P_lds writes before PV reads
    // --- PV: each V fragment read once, used by both q-groups ---
    __builtin_amdgcn_s_setprio(1);
#pragma unroll
    for (int kc = 0; kc < 2; ++kc) {
      const bf16x8 pa0 = *(const bf16x8*)&pl[a15 * 72 + kc * 32 + g * 8];
      const bf16x8 pa1 = *(const bf16x8*)&pl[(16 + a15) * 72 + kc * 32 + g * 8];
#pragma unroll
      for (int ni = 0; ni < 4; ++ni) {
        const int vrow = ni * 16 + a15;
        const char* vp = (const char*)&V_lds[cur][vrow * 64];
        const int vswz = (vrow & 7) << 4;
        const bf16x8 vb = *(const bf16x8*)(vp + ((kc * 64 + g * 16) ^ vswz));
        acc[0][ni] = __builtin_amdgcn_mfma_f32_16x16x32_bf16(pa0, vb, acc[0][ni], 0, 0, 0);
        acc[1][ni] = __builtin_amdgcn_mfma_f32_16x16x32_bf16(pa1, vb, acc[1][ni], 0, 0, 0);
      }
    }
    __builtin_amdgcn_s_setprio(0);
    __syncthreads();  // drains prefetch (landed under compute) + read/write fence
  }
#pragma unroll
  for (int qg = 0; qg < 2; ++qg) {
    float lsum = (ls[qg][0] + ls[qg][1]) + (ls[qg][2] + ls[qg][3]);
    lsum += __shfl_xor(lsum, 16);
    lsum += __shfl_xor(lsum, 32);
    const float li0 = 1.f / (__shfl(lsum, g * 4 + 0) + 1e-30f);
    const float li1 = 1.f / (__shfl(lsum, g * 4 + 1) + 1e-30f);
    const float li2 = 1.f / (__shfl(lsum, g * 4 + 2) + 1e-30f);
    const float li3 = 1.f / (__shfl(lsum, g * 4 + 3) + 1e-30f);
    const int obase = (b * 2048 + qx * 256 + wave * 32 + qg * 16 + g * 4) * 1024 + h * 64 + a15;
#pragma unroll
    for (int ni = 0; ni < 4; ++ni) {
      O[obase + 0 * 1024 + ni * 16] = f2b(acc[qg][ni][0] * li0);
      O[obase + 1 * 1024 + ni * 16] = f2b(acc[qg][ni][1] * li1);
      O[obase + 2 * 1024 + ni * 16] = f2b(acc[qg][ni][2] * li2);
      O[obase + 3 * 1024 + ni * 16] = f2b(acc[qg][ni][3] * li3);
    }
  }
}

extern "C" void kernel_launch(void* const* d_in, const int* in_sizes, int n_in,
                              void* d_out, int out_size, void* d_ws, size_t ws_size,
                              hipStream_t stream) {
  (void)in_sizes; (void)n_in; (void)out_size; (void)ws_size;
  const float* x   = (const float*)d_in[0];
  const float* xo  = (const float*)d_in[1];
  const float* dec = (const float*)d_in[2];
  const float* Wq  = (const float*)d_in[3];
  const float* Wk  = (const float*)d_in[4];
  const float* Wv  = (const float*)d_in[5];
  const float* Wp  = (const float*)d_in[6];
  float* out = (float*)d_out;

  // ws (40 MB): Wqt@0(2M) | Wkvt@2M(4M) | Wpt@6M(2M) | Qb@8M(16M, becomes O) |
  //   Vtb@24M(16M).
  // d_out (32 MiB) scratch before final overwrite: Kb@0 (16MiB bf16 K).
  char* ws = (char*)d_ws;
  u16* Wqt  = (u16*)(ws + ((size_t)0 << 20));
  u16* Wkvt = (u16*)(ws + ((size_t)2 << 20));
  u16* Wpt  = (u16*)(ws + ((size_t)6 << 20));
  u16* Qb   = (u16*)(ws + ((size_t)8 << 20));
  u16* Vtb  = (u16*)(ws + ((size_t)24 << 20));
  u16* Kb   = (u16*)d_out;

  const dim3 blk(256);
  transpose_w4<<<dim3(32, 32, 4), blk, 0, stream>>>(
      Wq, Wk, Wv, Wp, Wqt, Wkvt, Wkvt + 1024 * 1024, Wpt);

  gemm_fused<<<dim3(64, 24), blk, 0, stream>>>(x, xo, Wqt, Wkvt, Qb, Kb, Vtb);

  attn_kernel<<<dim3(512), dim3(512), 0, stream>>>(Qb, Kb, Vtb, dec, Qb);

  gemm_out<<<dim3(64, 8), blk, 0, stream>>>(Qb, Wpt, out);
}

// Round 16
// 196.765 us; speedup vs baseline: 1.0716x; 1.0716x over previous
//
#include <hip/hip_runtime.h>

typedef unsigned short u16;
typedef __attribute__((ext_vector_type(8))) short bf16x8;
typedef __attribute__((ext_vector_type(4))) short s16x4;
typedef __attribute__((ext_vector_type(4))) float f32x4;

#define GLDS(g, l) __builtin_amdgcn_global_load_lds( \
    (const __attribute__((address_space(1))) unsigned int*)(g), \
    (__attribute__((address_space(3))) unsigned int*)(l), 16, 0, 0)

__device__ __forceinline__ u16 f2b(float f) {
  unsigned int x = __float_as_uint(f);
  return (u16)((x + 0x7fffu + ((x >> 16) & 1u)) >> 16);
}
__device__ __forceinline__ bf16x8 cvt8(float4 a, float4 b) {
  bf16x8 r;
  r[0] = (short)f2b(a.x); r[1] = (short)f2b(a.y);
  r[2] = (short)f2b(a.z); r[3] = (short)f2b(a.w);
  r[4] = (short)f2b(b.x); r[5] = (short)f2b(b.y);
  r[6] = (short)f2b(b.z); r[7] = (short)f2b(b.w);
  return r;
}

// ---- merged prep: blocks [0,4096) = 4x weight transpose; [4096,8192) = xo->bf16 ----
// (one launch instead of two; per-block uniform branch, no divergence)
__global__ __launch_bounds__(256) void prep_all(
    const float* __restrict__ W0, const float* __restrict__ W1,
    const float* __restrict__ W2, const float* __restrict__ W3,
    u16* __restrict__ D0, u16* __restrict__ D1,
    u16* __restrict__ D2, u16* __restrict__ D3,
    const float* __restrict__ xo, u16* __restrict__ Xb) {
  const int id = blockIdx.x;
  if (id < 4096) {
    const int z = id >> 10, yy = (id >> 5) & 31, xx = id & 31;
    const float* W = (z == 0) ? W0 : (z == 1) ? W1 : (z == 2) ? W2 : W3;
    u16* Wt = (z == 0) ? D0 : (z == 1) ? D1 : (z == 2) ? D2 : D3;
    __shared__ u16 tile[32][33];
    const int tx = threadIdx.x & 31, ty = threadIdx.x >> 5;
    const int r0 = yy * 32, c0 = xx * 32;
#pragma unroll
    for (int i = 0; i < 32; i += 8)
      tile[ty + i][tx] = f2b(W[(r0 + ty + i) * 1024 + c0 + tx]);
    __syncthreads();
#pragma unroll
    for (int i = 0; i < 32; i += 8)
      Wt[(c0 + ty + i) * 1024 + r0 + tx] = tile[tx][ty + i];
  } else {
    const int i0 = ((id - 4096) * 256 + threadIdx.x) * 8;
    const float4 a = *(const float4*)&xo[i0];
    const float4 b = *(const float4*)&xo[i0 + 4];
    *(bf16x8*)&Xb[i0] = cvt8(a, b);
  }
}

// ------- FUSED Q + K + V projection GEMM: one launch, grid (64, 24) -------
// y<8:    Q-part:  A = x (f32, reg-staged->bf16 LDS, RNE == cvt kernel),
//                  Bt = Wqt, C = Qb row-major bf16, ccol = y*128.
// y in [8,24): KV-part: A = Xb (xo bf16, global_load_lds), Bt = Wkvt rows
//                  (y-8)*128; y-8<8 -> K row-major; else V^T scatter to Vtb.
// 128x128 tile, BK=32, 4 waves, 16x16x32 MFMA, double-buffered prefetch.
// (r14-proven hybrid: bf16 A for the 16 KV blocks keeps the y-replicated
// A-panel re-reads inside the 4MB/XCD L2; all-f32 regressed +35us in r15.)
__global__ __launch_bounds__(256) void gemm_fused(
    const float* __restrict__ Ax, const u16* __restrict__ Axo,
    const u16* __restrict__ Wqt, const u16* __restrict__ Wkvt,
    u16* __restrict__ Qb, u16* __restrict__ Kb, u16* __restrict__ Vtb) {
  __shared__ u16 As[2][128 * 32];
  __shared__ u16 Bs[2][128 * 32];
  const int t = threadIdx.x;
  const int wave = t >> 6, lane = t & 63;
  const int g = lane >> 4, a15 = lane & 15;
  const int wr = wave >> 1, wc = wave & 1;
  const int row0 = t >> 2;            // 0..63
  const int col0 = (t & 3) * 8;       // 0,8,16,24
  const int y = blockIdx.y;
  const bool qpart = (y < 8);
  const u16* Bt = qpart ? Wqt : Wkvt;
  const int yb = qpart ? y : (y - 8);
  const int abase = (blockIdx.x * 128 + row0) * 1024 + col0;
  const int bbase = (yb * 128 + row0) * 1024 + col0;

  f32x4 acc[4][4] = {};

  // ---- prologue: stage K-step 0 into buffer 0 ----
  GLDS(Bt + bbase, &Bs[0][wave * 512]);
  GLDS(Bt + bbase + 64 * 1024, &Bs[0][2048 + wave * 512]);
  if (qpart) {
    const float* Ag = Ax + abase;
    const float4 x0 = *(const float4*)(Ag);
    const float4 x1 = *(const float4*)(Ag + 4);
    const float4 y0 = *(const float4*)(Ag + 64 * 1024);
    const float4 y1 = *(const float4*)(Ag + 64 * 1024 + 4);
    *(bf16x8*)&As[0][row0 * 32 + col0] = cvt8(x0, x1);
    *(bf16x8*)&As[0][(row0 + 64) * 32 + col0] = cvt8(y0, y1);
  } else {
    GLDS(Axo + abase, &As[0][wave * 512]);
    GLDS(Axo + abase + 64 * 1024, &As[0][2048 + wave * 512]);
  }
  __syncthreads();

  for (int ki = 0; ki < 32; ++ki) {
    const int cur = ki & 1, nxt = cur ^ 1;
    const int ktn = (ki + 1) * 32;
    const bool pf = ki < 31;
    float4 x0, x1, y0, y1;
    if (pf) {
      GLDS(Bt + bbase + ktn, &Bs[nxt][wave * 512]);
      GLDS(Bt + bbase + 64 * 1024 + ktn, &Bs[nxt][2048 + wave * 512]);
      if (qpart) {
        const float* Ag = Ax + abase + ktn;
        x0 = *(const float4*)(Ag);
        x1 = *(const float4*)(Ag + 4);
        y0 = *(const float4*)(Ag + 64 * 1024);
        y1 = *(const float4*)(Ag + 64 * 1024 + 4);
      } else {
        GLDS(Axo + abase + ktn, &As[nxt][wave * 512]);
        GLDS(Axo + abase + 64 * 1024 + ktn, &As[nxt][2048 + wave * 512]);
      }
    }
    bf16x8 af[4], bfr[4];
#pragma unroll
    for (int mi = 0; mi < 4; ++mi)
      af[mi] = *(const bf16x8*)&As[cur][(wr * 64 + mi * 16 + a15) * 32 + g * 8];
#pragma unroll
    for (int ni = 0; ni < 4; ++ni)
      bfr[ni] = *(const bf16x8*)&Bs[cur][(wc * 64 + ni * 16 + a15) * 32 + g * 8];
#pragma unroll
    for (int mi = 0; mi < 4; ++mi)
#pragma unroll
      for (int ni = 0; ni < 4; ++ni)
        acc[mi][ni] = __builtin_amdgcn_mfma_f32_16x16x32_bf16(af[mi], bfr[ni], acc[mi][ni], 0, 0, 0);
    if (pf && qpart) {
      *(bf16x8*)&As[nxt][row0 * 32 + col0] = cvt8(x0, x1);
      *(bf16x8*)&As[nxt][(row0 + 64) * 32 + col0] = cvt8(y0, y1);
    }
    __syncthreads();
  }

  const int crow = blockIdx.x * 128 + wr * 64 + g * 4;
  const int ccol = yb * 128 + wc * 64 + a15;
  if (qpart) {
#pragma unroll
    for (int mi = 0; mi < 4; ++mi)
#pragma unroll
      for (int ni = 0; ni < 4; ++ni)
#pragma unroll
        for (int r = 0; r < 4; ++r)
          Qb[(crow + mi * 16 + r) * 1024 + ccol + ni * 16] = f2b(acc[mi][ni][r]);
  } else if (yb < 8) {
#pragma unroll
    for (int mi = 0; mi < 4; ++mi)
#pragma unroll
      for (int ni = 0; ni < 4; ++ni)
#pragma unroll
        for (int r = 0; r < 4; ++r)
          Kb[(crow + mi * 16 + r) * 1024 + ccol + ni * 16] = f2b(acc[mi][ni][r]);
  } else {
    // V part: Vt[((b*16+h)*64 + dd)*2048 + n], col c = ccol - 1024
#pragma unroll
    for (int mi = 0; mi < 4; ++mi) {
      const int n = crow + mi * 16;
      const int bq = n >> 11;
      const int nl = n & 2047;
#pragma unroll
      for (int ni = 0; ni < 4; ++ni) {
        const int c = ccol + ni * 16 - 1024;
        s16x4 v4;
        v4[0] = (short)f2b(acc[mi][ni][0]);
        v4[1] = (short)f2b(acc[mi][ni][1]);
        v4[2] = (short)f2b(acc[mi][ni][2]);
        v4[3] = (short)f2b(acc[mi][ni][3]);
        *(s16x4*)&Vtb[(((bq << 4) + (c >> 6)) * 64 + (c & 63)) * 2048 + nl] = v4;
      }
    }
  }
}

// ---------------- out-GEMM: C(f32) = A(bf16) * Bt^T, same 128^2 dbuf core ----------------
__global__ __launch_bounds__(256) void gemm_out(const u16* __restrict__ A,
                                                const u16* __restrict__ Bt,
                                                float* __restrict__ C) {
  __shared__ u16 As[2][128 * 32];
  __shared__ u16 Bs[2][128 * 32];
  const int t = threadIdx.x;
  const int wave = t >> 6, lane = t & 63;
  const int g = lane >> 4, a15 = lane & 15;
  const int wr = wave >> 1, wc = wave & 1;
  const int row0 = t >> 2;
  const int col0 = (t & 3) * 8;
  const int abase = (blockIdx.x * 128 + row0) * 1024 + col0;
  const int bbase = (blockIdx.y * 128 + row0) * 1024 + col0;

  f32x4 acc[4][4] = {};

  GLDS(A + abase, &As[0][wave * 512]);
  GLDS(A + abase + 64 * 1024, &As[0][2048 + wave * 512]);
  GLDS(Bt + bbase, &Bs[0][wave * 512]);
  GLDS(Bt + bbase + 64 * 1024, &Bs[0][2048 + wave * 512]);
  __syncthreads();

  for (int ki = 0; ki < 32; ++ki) {
    const int cur = ki & 1, nxt = cur ^ 1;
    const int ktn = (ki + 1) * 32;
    if (ki < 31) {
      GLDS(A + abase + ktn, &As[nxt][wave * 512]);
      GLDS(A + abase + 64 * 1024 + ktn, &As[nxt][2048 + wave * 512]);
      GLDS(Bt + bbase + ktn, &Bs[nxt][wave * 512]);
      GLDS(Bt + bbase + 64 * 1024 + ktn, &Bs[nxt][2048 + wave * 512]);
    }
    bf16x8 af[4], bfr[4];
#pragma unroll
    for (int mi = 0; mi < 4; ++mi)
      af[mi] = *(const bf16x8*)&As[cur][(wr * 64 + mi * 16 + a15) * 32 + g * 8];
#pragma unroll
    for (int ni = 0; ni < 4; ++ni)
      bfr[ni] = *(const bf16x8*)&Bs[cur][(wc * 64 + ni * 16 + a15) * 32 + g * 8];
#pragma unroll
    for (int mi = 0; mi < 4; ++mi)
#pragma unroll
      for (int ni = 0; ni < 4; ++ni)
        acc[mi][ni] = __builtin_amdgcn_mfma_f32_16x16x32_bf16(af[mi], bfr[ni], acc[mi][ni], 0, 0, 0);
    __syncthreads();
  }

  const int crow = blockIdx.x * 128 + wr * 64 + g * 4;
  const int ccol = blockIdx.y * 128 + wc * 64 + a15;
#pragma unroll
  for (int mi = 0; mi < 4; ++mi)
#pragma unroll
    for (int ni = 0; ni < 4; ++ni)
#pragma unroll
      for (int r = 0; r < 4; ++r)
        C[(crow + mi * 16 + r) * 1024 + ccol + ni * 16] = acc[mi][ni][r];
}

// ---------------- flash attention (r13/r14-proven version, exact revert) ----------------
// 512-thread blocks (8 waves) sharing one K/V tile; grid 512 = 2 blocks/CU
// (16 waves/CU). Fixed-shift log2-domain softmax (exact by shift-invariance;
// EPS terms <=1e-8). O aliases Q (disjoint per-wave read/write regions).
// NOTE: no setprio (r15 A/B: -10% on this lockstep structure, T5/m190 confirmed).
__global__ __launch_bounds__(512) void attn_kernel(
    const u16* Q, const u16* __restrict__ K,
    const u16* __restrict__ Vt, const float* __restrict__ dec,
    u16* O) {
  const int f = blockIdx.x;
  const int bh = (f & 7) * 8 + ((f >> 3) & 7);   // 8 heads per XCD
  const int qx = f >> 6;                          // [0,8) q-tile of 256 rows
  const int b = bh >> 4, h = bh & 15;
  __shared__ u16 K_lds[2][64 * 64];
  __shared__ u16 V_lds[2][64 * 64];
  __shared__ __align__(16) u16 P_lds[8][32 * 72];
  __shared__ float l2p_lds[2048];

  const int wave = threadIdx.x >> 6, lane = threadIdx.x & 63;
  const int g = lane >> 4, a15 = lane & 15;
  u16* pl = &P_lds[wave][0];

  {
    const int i0 = threadIdx.x * 4;
    const float4 d0 = *(const float4*)&dec[b * 2048 + i0];
    float4 o0;
    o0.x = __log2f(fmaxf(1.f - d0.x, 1e-38f));
    o0.y = __log2f(fmaxf(1.f - d0.y, 1e-38f));
    o0.z = __log2f(fmaxf(1.f - d0.z, 1e-38f));
    o0.w = __log2f(fmaxf(1.f - d0.w, 1e-38f));
    *(float4*)&l2p_lds[i0] = o0;
  }

  bf16x8 qf[2][2];
  {
    const int qr = (b * 2048 + qx * 256 + wave * 32 + a15) * 1024 + h * 64 + g * 8;
#pragma unroll
    for (int qg = 0; qg < 2; ++qg) {
      qf[qg][0] = *(const bf16x8*)&Q[qr + qg * 16 * 1024];
      qf[qg][1] = *(const bf16x8*)&Q[qr + qg * 16 * 1024 + 32];
    }
  }

  const int srow = lane >> 3;
  const int swze = (((lane & 7) * 16) ^ (srow << 4)) >> 1;  // u16 elems
  const u16* Kg = K + ((size_t)(b * 2048 + wave * 8 + srow)) * 1024 + h * 64 + swze;
  const u16* Vg = Vt + ((size_t)(bh * 64 + wave * 8 + srow)) * 2048 + swze;
  u16* kdst[2] = {&K_lds[0][wave * 8 * 64], &K_lds[1][wave * 8 * 64]};
  u16* vdst[2] = {&V_lds[0][wave * 8 * 64], &V_lds[1][wave * 8 * 64]};

  GLDS(Kg, kdst[0]);
  GLDS(Vg, vdst[0]);
  __syncthreads();

  const float CSC = 0.125f * 1.44269504f;  // scale * log2(e)
  f32x4 acc[2][4] = {};
  f32x4 ls[2] = {};

  for (int it = 0; it < 32; ++it) {
    const int cur = it & 1, nxt = cur ^ 1;
    if (it < 31) {
      const int ktn = (it + 1) * 64;
      GLDS(Kg + (size_t)ktn * 1024, kdst[nxt]);
      GLDS(Vg + ktn, vdst[nxt]);
    }
    const int kt = it * 64;
    f32x4 sf[2][4];
#pragma unroll
    for (int sub = 0; sub < 4; ++sub) {
      const int krow = sub * 16 + a15;
      const char* kp = (const char*)&K_lds[cur][krow * 64];
      const int swz = (krow & 7) << 4;
      const bf16x8 k0 = *(const bf16x8*)(kp + ((g * 16) ^ swz));
      const bf16x8 k1 = *(const bf16x8*)(kp + ((g * 16 + 64) ^ swz));
#pragma unroll
      for (int qg = 0; qg < 2; ++qg) {
        f32x4 s = {0.f, 0.f, 0.f, 0.f};
        s = __builtin_amdgcn_mfma_f32_16x16x32_bf16(k0, qf[qg][0], s, 0, 0, 0);
        s = __builtin_amdgcn_mfma_f32_16x16x32_bf16(k1, qf[qg][1], s, 0, 0, 0);
        sf[qg][sub] = s;
      }
    }
#pragma unroll
    for (int qg = 0; qg < 2; ++qg) {
#pragma unroll
      for (int sub = 0; sub < 4; ++sub) {
        const float4 lp = *(const float4*)&l2p_lds[kt + sub * 16 + g * 4];
        const float e0 = __builtin_amdgcn_exp2f(fmaf(sf[qg][sub][0], CSC, lp.x));
        const float e1 = __builtin_amdgcn_exp2f(fmaf(sf[qg][sub][1], CSC, lp.y));
        const float e2 = __builtin_amdgcn_exp2f(fmaf(sf[qg][sub][2], CSC, lp.z));
        const float e3 = __builtin_amdgcn_exp2f(fmaf(sf[qg][sub][3], CSC, lp.w));
        ls[qg][0] += e0; ls[qg][1] += e1; ls[qg][2] += e2; ls[qg][3] += e3;
        unsigned int w0, w1;
        asm("v_cvt_pk_bf16_f32 %0, %1, %2" : "=v"(w0) : "v"(e0), "v"(e1));
        asm("v_cvt_pk_bf16_f32 %0, %1, %2" : "=v"(w1) : "v"(e2), "v"(e3));
        uint2 w; w.x = w0; w.y = w1;
        *(uint2*)&pl[(qg * 16 + a15) * 72 + sub * 16 + g * 4] = w;
      }
    }
    asm volatile("" ::: "memory");
#pragma unroll
    for (int kc = 0; kc < 2; ++kc) {
      const bf16x8 pa0 = *(const bf16x8*)&pl[a15 * 72 + kc * 32 + g * 8];
      const bf16x8 pa1 = *(const bf16x8*)&pl[(16 + a15) * 72 + kc * 32 + g * 8];
#pragma unroll
      for (int ni = 0; ni < 4; ++ni) {
        const int vrow = ni * 16 + a15;
        const char* vp = (const char*)&V_lds[cur][vrow * 64];
        const int vswz = (vrow & 7) << 4;
        const bf16x8 vb = *(const bf16x8*)(vp + ((kc * 64 + g * 16) ^ vswz));
        acc[0][ni] = __builtin_amdgcn_mfma_f32_16x16x32_bf16(pa0, vb, acc[0][ni], 0, 0, 0);
        acc[1][ni] = __builtin_amdgcn_mfma_f32_16x16x32_bf16(pa1, vb, acc[1][ni], 0, 0, 0);
      }
    }
    __syncthreads();
  }
#pragma unroll
  for (int qg = 0; qg < 2; ++qg) {
    float lsum = (ls[qg][0] + ls[qg][1]) + (ls[qg][2] + ls[qg][3]);
    lsum += __shfl_xor(lsum, 16);
    lsum += __shfl_xor(lsum, 32);
    const float li0 = 1.f / (__shfl(lsum, g * 4 + 0) + 1e-30f);
    const float li1 = 1.f / (__shfl(lsum, g * 4 + 1) + 1e-30f);
    const float li2 = 1.f / (__shfl(lsum, g * 4 + 2) + 1e-30f);
    const float li3 = 1.f / (__shfl(lsum, g * 4 + 3) + 1e-30f);
    const int obase = (b * 2048 + qx * 256 + wave * 32 + qg * 16 + g * 4) * 1024 + h * 64 + a15;
#pragma unroll
    for (int ni = 0; ni < 4; ++ni) {
      O[obase + 0 * 1024 + ni * 16] = f2b(acc[qg][ni][0] * li0);
      O[obase + 1 * 1024 + ni * 16] = f2b(acc[qg][ni][1] * li1);
      O[obase + 2 * 1024 + ni * 16] = f2b(acc[qg][ni][2] * li2);
      O[obase + 3 * 1024 + ni * 16] = f2b(acc[qg][ni][3] * li3);
    }
  }
}

extern "C" void kernel_launch(void* const* d_in, const int* in_sizes, int n_in,
                              void* d_out, int out_size, void* d_ws, size_t ws_size,
                              hipStream_t stream) {
  (void)in_sizes; (void)n_in; (void)out_size; (void)ws_size;
  const float* x   = (const float*)d_in[0];
  const float* xo  = (const float*)d_in[1];
  const float* dec = (const float*)d_in[2];
  const float* Wq  = (const float*)d_in[3];
  const float* Wk  = (const float*)d_in[4];
  const float* Wv  = (const float*)d_in[5];
  const float* Wp  = (const float*)d_in[6];
  float* out = (float*)d_out;

  // ws (40 MB): Wqt@0(2M) | Wkvt@2M(4M) | Wpt@6M(2M) | Qb@8M(16M, becomes O) |
  //   Vtb@24M(16M).
  // d_out (32 MiB) scratch before final overwrite: Kb@0 (16MiB bf16 K),
  // Xb@16MiB (16MiB bf16 xo).
  char* ws = (char*)d_ws;
  u16* Wqt  = (u16*)(ws + ((size_t)0 << 20));
  u16* Wkvt = (u16*)(ws + ((size_t)2 << 20));
  u16* Wpt  = (u16*)(ws + ((size_t)6 << 20));
  u16* Qb   = (u16*)(ws + ((size_t)8 << 20));
  u16* Vtb  = (u16*)(ws + ((size_t)24 << 20));
  u16* Kb   = (u16*)d_out;
  u16* Xb   = (u16*)((char*)d_out + ((size_t)16 << 20));

  const dim3 blk(256);
  prep_all<<<dim3(8192), blk, 0, stream>>>(
      Wq, Wk, Wv, Wp, Wqt, Wkvt, Wkvt + 1024 * 1024, Wpt, xo, Xb);

  gemm_fused<<<dim3(64, 24), blk, 0, stream>>>(x, Xb, Wqt, Wkvt, Qb, Kb, Vtb);

  attn_kernel<<<dim3(512), dim3(512), 0, stream>>>(Qb, Kb, Vtb, dec, Qb);

  gemm_out<<<dim3(64, 8), blk, 0, stream>>>(Qb, Wpt, out);
}

// Round 18
// 196.671 us; speedup vs baseline: 1.0722x; 1.0005x over previous
//
#include <hip/hip_runtime.h>

typedef unsigned short u16;
typedef __attribute__((ext_vector_type(8))) short bf16x8;
typedef __attribute__((ext_vector_type(4))) short s16x4;
typedef __attribute__((ext_vector_type(4))) float f32x4;

#define GLDS(g, l) __builtin_amdgcn_global_load_lds( \
    (const __attribute__((address_space(1))) unsigned int*)(g), \
    (__attribute__((address_space(3))) unsigned int*)(l), 16, 0, 0)

__device__ __forceinline__ u16 f2b(float f) {
  unsigned int x = __float_as_uint(f);
  return (u16)((x + 0x7fffu + ((x >> 16) & 1u)) >> 16);
}
__device__ __forceinline__ bf16x8 cvt8(float4 a, float4 b) {
  bf16x8 r;
  r[0] = (short)f2b(a.x); r[1] = (short)f2b(a.y);
  r[2] = (short)f2b(a.z); r[3] = (short)f2b(a.w);
  r[4] = (short)f2b(b.x); r[5] = (short)f2b(b.y);
  r[6] = (short)f2b(b.z); r[7] = (short)f2b(b.w);
  return r;
}

// ---- merged prep: blocks [0,4096) = 4x weight transpose; [4096,8192) = xo->bf16 ----
__global__ __launch_bounds__(256) void prep_all(
    const float* __restrict__ W0, const float* __restrict__ W1,
    const float* __restrict__ W2, const float* __restrict__ W3,
    u16* __restrict__ D0, u16* __restrict__ D1,
    u16* __restrict__ D2, u16* __restrict__ D3,
    const float* __restrict__ xo, u16* __restrict__ Xb) {
  const int id = blockIdx.x;
  if (id < 4096) {
    const int z = id >> 10, yy = (id >> 5) & 31, xx = id & 31;
    const float* W = (z == 0) ? W0 : (z == 1) ? W1 : (z == 2) ? W2 : W3;
    u16* Wt = (z == 0) ? D0 : (z == 1) ? D1 : (z == 2) ? D2 : D3;
    __shared__ u16 tile[32][33];
    const int tx = threadIdx.x & 31, ty = threadIdx.x >> 5;
    const int r0 = yy * 32, c0 = xx * 32;
#pragma unroll
    for (int i = 0; i < 32; i += 8)
      tile[ty + i][tx] = f2b(W[(r0 + ty + i) * 1024 + c0 + tx]);
    __syncthreads();
#pragma unroll
    for (int i = 0; i < 32; i += 8)
      Wt[(c0 + ty + i) * 1024 + r0 + tx] = tile[tx][ty + i];
  } else {
    const int i0 = ((id - 4096) * 256 + threadIdx.x) * 8;
    const float4 a = *(const float4*)&xo[i0];
    const float4 b = *(const float4*)&xo[i0 + 4];
    *(bf16x8*)&Xb[i0] = cvt8(a, b);
  }
}

// ------- FUSED Q + K + V projection GEMM: one launch, grid (64, 24) -------
// y<8: Q-part (A = x f32 reg-staged); y in [8,24): KV-part (A = Xb bf16 GLDS).
// 128x128 tile, BK=32, 4 waves, 16x16x32 MFMA, double-buffered prefetch.
__global__ __launch_bounds__(256) void gemm_fused(
    const float* __restrict__ Ax, const u16* __restrict__ Axo,
    const u16* __restrict__ Wqt, const u16* __restrict__ Wkvt,
    u16* __restrict__ Qb, u16* __restrict__ Kb, u16* __restrict__ Vtb) {
  __shared__ u16 As[2][128 * 32];
  __shared__ u16 Bs[2][128 * 32];
  const int t = threadIdx.x;
  const int wave = t >> 6, lane = t & 63;
  const int g = lane >> 4, a15 = lane & 15;
  const int wr = wave >> 1, wc = wave & 1;
  const int row0 = t >> 2;            // 0..63
  const int col0 = (t & 3) * 8;       // 0,8,16,24
  const int y = blockIdx.y;
  const bool qpart = (y < 8);
  const u16* Bt = qpart ? Wqt : Wkvt;
  const int yb = qpart ? y : (y - 8);
  const int abase = (blockIdx.x * 128 + row0) * 1024 + col0;
  const int bbase = (yb * 128 + row0) * 1024 + col0;

  f32x4 acc[4][4] = {};

  GLDS(Bt + bbase, &Bs[0][wave * 512]);
  GLDS(Bt + bbase + 64 * 1024, &Bs[0][2048 + wave * 512]);
  if (qpart) {
    const float* Ag = Ax + abase;
    const float4 x0 = *(const float4*)(Ag);
    const float4 x1 = *(const float4*)(Ag + 4);
    const float4 y0 = *(const float4*)(Ag + 64 * 1024);
    const float4 y1 = *(const float4*)(Ag + 64 * 1024 + 4);
    *(bf16x8*)&As[0][row0 * 32 + col0] = cvt8(x0, x1);
    *(bf16x8*)&As[0][(row0 + 64) * 32 + col0] = cvt8(y0, y1);
  } else {
    GLDS(Axo + abase, &As[0][wave * 512]);
    GLDS(Axo + abase + 64 * 1024, &As[0][2048 + wave * 512]);
  }
  __syncthreads();

  for (int ki = 0; ki < 32; ++ki) {
    const int cur = ki & 1, nxt = cur ^ 1;
    const int ktn = (ki + 1) * 32;
    const bool pf = ki < 31;
    float4 x0, x1, y0, y1;
    if (pf) {
      GLDS(Bt + bbase + ktn, &Bs[nxt][wave * 512]);
      GLDS(Bt + bbase + 64 * 1024 + ktn, &Bs[nxt][2048 + wave * 512]);
      if (qpart) {
        const float* Ag = Ax + abase + ktn;
        x0 = *(const float4*)(Ag);
        x1 = *(const float4*)(Ag + 4);
        y0 = *(const float4*)(Ag + 64 * 1024);
        y1 = *(const float4*)(Ag + 64 * 1024 + 4);
      } else {
        GLDS(Axo + abase + ktn, &As[nxt][wave * 512]);
        GLDS(Axo + abase + 64 * 1024 + ktn, &As[nxt][2048 + wave * 512]);
      }
    }
    bf16x8 af[4], bfr[4];
#pragma unroll
    for (int mi = 0; mi < 4; ++mi)
      af[mi] = *(const bf16x8*)&As[cur][(wr * 64 + mi * 16 + a15) * 32 + g * 8];
#pragma unroll
    for (int ni = 0; ni < 4; ++ni)
      bfr[ni] = *(const bf16x8*)&Bs[cur][(wc * 64 + ni * 16 + a15) * 32 + g * 8];
#pragma unroll
    for (int mi = 0; mi < 4; ++mi)
#pragma unroll
      for (int ni = 0; ni < 4; ++ni)
        acc[mi][ni] = __builtin_amdgcn_mfma_f32_16x16x32_bf16(af[mi], bfr[ni], acc[mi][ni], 0, 0, 0);
    if (pf && qpart) {
      *(bf16x8*)&As[nxt][row0 * 32 + col0] = cvt8(x0, x1);
      *(bf16x8*)&As[nxt][(row0 + 64) * 32 + col0] = cvt8(y0, y1);
    }
    __syncthreads();
  }

  const int crow = blockIdx.x * 128 + wr * 64 + g * 4;
  const int ccol = yb * 128 + wc * 64 + a15;
  if (qpart) {
#pragma unroll
    for (int mi = 0; mi < 4; ++mi)
#pragma unroll
      for (int ni = 0; ni < 4; ++ni)
#pragma unroll
        for (int r = 0; r < 4; ++r)
          Qb[(crow + mi * 16 + r) * 1024 + ccol + ni * 16] = f2b(acc[mi][ni][r]);
  } else if (yb < 8) {
#pragma unroll
    for (int mi = 0; mi < 4; ++mi)
#pragma unroll
      for (int ni = 0; ni < 4; ++ni)
#pragma unroll
        for (int r = 0; r < 4; ++r)
          Kb[(crow + mi * 16 + r) * 1024 + ccol + ni * 16] = f2b(acc[mi][ni][r]);
  } else {
    // V part: Vt[((b*16+h)*64 + dd)*2048 + n], col c = ccol - 1024
#pragma unroll
    for (int mi = 0; mi < 4; ++mi) {
      const int n = crow + mi * 16;
      const int bq = n >> 11;
      const int nl = n & 2047;
#pragma unroll
      for (int ni = 0; ni < 4; ++ni) {
        const int c = ccol + ni * 16 - 1024;
        s16x4 v4;
        v4[0] = (short)f2b(acc[mi][ni][0]);
        v4[1] = (short)f2b(acc[mi][ni][1]);
        v4[2] = (short)f2b(acc[mi][ni][2]);
        v4[3] = (short)f2b(acc[mi][ni][3]);
        *(s16x4*)&Vtb[(((bq << 4) + (c >> 6)) * 64 + (c & 63)) * 2048 + nl] = v4;
      }
    }
  }
}

// ---------------- out-GEMM: C(f32) = A(bf16) * Bt^T, same 128^2 dbuf core ----------------
__global__ __launch_bounds__(256) void gemm_out(const u16* __restrict__ A,
                                                const u16* __restrict__ Bt,
                                                float* __restrict__ C) {
  __shared__ u16 As[2][128 * 32];
  __shared__ u16 Bs[2][128 * 32];
  const int t = threadIdx.x;
  const int wave = t >> 6, lane = t & 63;
  const int g = lane >> 4, a15 = lane & 15;
  const int wr = wave >> 1, wc = wave & 1;
  const int row0 = t >> 2;
  const int col0 = (t & 3) * 8;
  const int abase = (blockIdx.x * 128 + row0) * 1024 + col0;
  const int bbase = (blockIdx.y * 128 + row0) * 1024 + col0;

  f32x4 acc[4][4] = {};

  GLDS(A + abase, &As[0][wave * 512]);
  GLDS(A + abase + 64 * 1024, &As[0][2048 + wave * 512]);
  GLDS(Bt + bbase, &Bs[0][wave * 512]);
  GLDS(Bt + bbase + 64 * 1024, &Bs[0][2048 + wave * 512]);
  __syncthreads();

  for (int ki = 0; ki < 32; ++ki) {
    const int cur = ki & 1, nxt = cur ^ 1;
    const int ktn = (ki + 1) * 32;
    if (ki < 31) {
      GLDS(A + abase + ktn, &As[nxt][wave * 512]);
      GLDS(A + abase + 64 * 1024 + ktn, &As[nxt][2048 + wave * 512]);
      GLDS(Bt + bbase + ktn, &Bs[nxt][wave * 512]);
      GLDS(Bt + bbase + 64 * 1024 + ktn, &Bs[nxt][2048 + wave * 512]);
    }
    bf16x8 af[4], bfr[4];
#pragma unroll
    for (int mi = 0; mi < 4; ++mi)
      af[mi] = *(const bf16x8*)&As[cur][(wr * 64 + mi * 16 + a15) * 32 + g * 8];
#pragma unroll
    for (int ni = 0; ni < 4; ++ni)
      bfr[ni] = *(const bf16x8*)&Bs[cur][(wc * 64 + ni * 16 + a15) * 32 + g * 8];
#pragma unroll
    for (int mi = 0; mi < 4; ++mi)
#pragma unroll
      for (int ni = 0; ni < 4; ++ni)
        acc[mi][ni] = __builtin_amdgcn_mfma_f32_16x16x32_bf16(af[mi], bfr[ni], acc[mi][ni], 0, 0, 0);
    __syncthreads();
  }

  const int crow = blockIdx.x * 128 + wr * 64 + g * 4;
  const int ccol = blockIdx.y * 128 + wc * 64 + a15;
#pragma unroll
  for (int mi = 0; mi < 4; ++mi)
#pragma unroll
    for (int ni = 0; ni < 4; ++ni)
#pragma unroll
      for (int r = 0; r < 4; ++r)
        C[(crow + mi * 16 + r) * 1024 + ccol + ni * 16] = acc[mi][ni][r];
}

// ---------------- flash attention (r13/r16-proven version, exact) ----------------
// 512-thread blocks (8 waves) sharing one K/V tile; grid 512 = 2 blocks/CU
// (16 waves/CU). Fixed-shift log2-domain softmax (exact by shift-invariance;
// EPS terms <=1e-8). O aliases Q (disjoint per-wave read/write regions).
// No setprio (r15: -10%); lsum on VALU + shfl epilogue (r17 MFMA variant broke).
__global__ __launch_bounds__(512) void attn_kernel(
    const u16* Q, const u16* __restrict__ K,
    const u16* __restrict__ Vt, const float* __restrict__ dec,
    u16* O) {
  const int f = blockIdx.x;
  const int bh = (f & 7) * 8 + ((f >> 3) & 7);   // 8 heads per XCD
  const int qx = f >> 6;                          // [0,8) q-tile of 256 rows
  const int b = bh >> 4, h = bh & 15;
  __shared__ u16 K_lds[2][64 * 64];
  __shared__ u16 V_lds[2][64 * 64];
  __shared__ __align__(16) u16 P_lds[8][32 * 72];
  __shared__ float l2p_lds[2048];

  const int wave = threadIdx.x >> 6, lane = threadIdx.x & 63;
  const int g = lane >> 4, a15 = lane & 15;
  u16* pl = &P_lds[wave][0];

  {
    const int i0 = threadIdx.x * 4;
    const float4 d0 = *(const float4*)&dec[b * 2048 + i0];
    float4 o0;
    o0.x = __log2f(fmaxf(1.f - d0.x, 1e-38f));
    o0.y = __log2f(fmaxf(1.f - d0.y, 1e-38f));
    o0.z = __log2f(fmaxf(1.f - d0.z, 1e-38f));
    o0.w = __log2f(fmaxf(1.f - d0.w, 1e-38f));
    *(float4*)&l2p_lds[i0] = o0;
  }

  bf16x8 qf[2][2];
  {
    const int qr = (b * 2048 + qx * 256 + wave * 32 + a15) * 1024 + h * 64 + g * 8;
#pragma unroll
    for (int qg = 0; qg < 2; ++qg) {
      qf[qg][0] = *(const bf16x8*)&Q[qr + qg * 16 * 1024];
      qf[qg][1] = *(const bf16x8*)&Q[qr + qg * 16 * 1024 + 32];
    }
  }

  const int srow = lane >> 3;
  const int swze = (((lane & 7) * 16) ^ (srow << 4)) >> 1;  // u16 elems
  const u16* Kg = K + ((size_t)(b * 2048 + wave * 8 + srow)) * 1024 + h * 64 + swze;
  const u16* Vg = Vt + ((size_t)(bh * 64 + wave * 8 + srow)) * 2048 + swze;
  u16* kdst[2] = {&K_lds[0][wave * 8 * 64], &K_lds[1][wave * 8 * 64]};
  u16* vdst[2] = {&V_lds[0][wave * 8 * 64], &V_lds[1][wave * 8 * 64]};

  GLDS(Kg, kdst[0]);
  GLDS(Vg, vdst[0]);
  __syncthreads();

  const float CSC = 0.125f * 1.44269504f;  // scale * log2(e)
  f32x4 acc[2][4] = {};
  f32x4 ls[2] = {};

  for (int it = 0; it < 32; ++it) {
    const int cur = it & 1, nxt = cur ^ 1;
    if (it < 31) {
      const int ktn = (it + 1) * 64;
      GLDS(Kg + (size_t)ktn * 1024, kdst[nxt]);
      GLDS(Vg + ktn, vdst[nxt]);
    }
    const int kt = it * 64;
    f32x4 sf[2][4];
#pragma unroll
    for (int sub = 0; sub < 4; ++sub) {
      const int krow = sub * 16 + a15;
      const char* kp = (const char*)&K_lds[cur][krow * 64];
      const int swz = (krow & 7) << 4;
      const bf16x8 k0 = *(const bf16x8*)(kp + ((g * 16) ^ swz));
      const bf16x8 k1 = *(const bf16x8*)(kp + ((g * 16 + 64) ^ swz));
#pragma unroll
      for (int qg = 0; qg < 2; ++qg) {
        f32x4 s = {0.f, 0.f, 0.f, 0.f};
        s = __builtin_amdgcn_mfma_f32_16x16x32_bf16(k0, qf[qg][0], s, 0, 0, 0);
        s = __builtin_amdgcn_mfma_f32_16x16x32_bf16(k1, qf[qg][1], s, 0, 0, 0);
        sf[qg][sub] = s;
      }
    }
#pragma unroll
    for (int qg = 0; qg < 2; ++qg) {
#pragma unroll
      for (int sub = 0; sub < 4; ++sub) {
        const float4 lp = *(const float4*)&l2p_lds[kt + sub * 16 + g * 4];
        const float e0 = __builtin_amdgcn_exp2f(fmaf(sf[qg][sub][0], CSC, lp.x));
        const float e1 = __builtin_amdgcn_exp2f(fmaf(sf[qg][sub][1], CSC, lp.y));
        const float e2 = __builtin_amdgcn_exp2f(fmaf(sf[qg][sub][2], CSC, lp.z));
        const float e3 = __builtin_amdgcn_exp2f(fmaf(sf[qg][sub][3], CSC, lp.w));
        ls[qg][0] += e0; ls[qg][1] += e1; ls[qg][2] += e2; ls[qg][3] += e3;
        unsigned int w0, w1;
        asm("v_cvt_pk_bf16_f32 %0, %1, %2" : "=v"(w0) : "v"(e0), "v"(e1));
        asm("v_cvt_pk_bf16_f32 %0, %1, %2" : "=v"(w1) : "v"(e2), "v"(e3));
        uint2 w; w.x = w0; w.y = w1;
        *(uint2*)&pl[(qg * 16 + a15) * 72 + sub * 16 + g * 4] = w;
      }
    }
    asm volatile("" ::: "memory");
#pragma unroll
    for (int kc = 0; kc < 2; ++kc) {
      const bf16x8 pa0 = *(const bf16x8*)&pl[a15 * 72 + kc * 32 + g * 8];
      const bf16x8 pa1 = *(const bf16x8*)&pl[(16 + a15) * 72 + kc * 32 + g * 8];
#pragma unroll
      for (int ni = 0; ni < 4; ++ni) {
        const int vrow = ni * 16 + a15;
        const char* vp = (const char*)&V_lds[cur][vrow * 64];
        const int vswz = (vrow & 7) << 4;
        const bf16x8 vb = *(const bf16x8*)(vp + ((kc * 64 + g * 16) ^ vswz));
        acc[0][ni] = __builtin_amdgcn_mfma_f32_16x16x32_bf16(pa0, vb, acc[0][ni], 0, 0, 0);
        acc[1][ni] = __builtin_amdgcn_mfma_f32_16x16x32_bf16(pa1, vb, acc[1][ni], 0, 0, 0);
      }
    }
    __syncthreads();
  }
#pragma unroll
  for (int qg = 0; qg < 2; ++qg) {
    float lsum = (ls[qg][0] + ls[qg][1]) + (ls[qg][2] + ls[qg][3]);
    lsum += __shfl_xor(lsum, 16);
    lsum += __shfl_xor(lsum, 32);
    const float li0 = 1.f / (__shfl(lsum, g * 4 + 0) + 1e-30f);
    const float li1 = 1.f / (__shfl(lsum, g * 4 + 1) + 1e-30f);
    const float li2 = 1.f / (__shfl(lsum, g * 4 + 2) + 1e-30f);
    const float li3 = 1.f / (__shfl(lsum, g * 4 + 3) + 1e-30f);
    const int obase = (b * 2048 + qx * 256 + wave * 32 + qg * 16 + g * 4) * 1024 + h * 64 + a15;
#pragma unroll
    for (int ni = 0; ni < 4; ++ni) {
      O[obase + 0 * 1024 + ni * 16] = f2b(acc[qg][ni][0] * li0);
      O[obase + 1 * 1024 + ni * 16] = f2b(acc[qg][ni][1] * li1);
      O[obase + 2 * 1024 + ni * 16] = f2b(acc[qg][ni][2] * li2);
      O[obase + 3 * 1024 + ni * 16] = f2b(acc[qg][ni][3] * li3);
    }
  }
}

extern "C" void kernel_launch(void* const* d_in, const int* in_sizes, int n_in,
                              void* d_out, int out_size, void* d_ws, size_t ws_size,
                              hipStream_t stream) {
  (void)in_sizes; (void)n_in; (void)out_size; (void)ws_size;
  const float* x   = (const float*)d_in[0];
  const float* xo  = (const float*)d_in[1];
  const float* dec = (const float*)d_in[2];
  const float* Wq  = (const float*)d_in[3];
  const float* Wk  = (const float*)d_in[4];
  const float* Wv  = (const float*)d_in[5];
  const float* Wp  = (const float*)d_in[6];
  float* out = (float*)d_out;

  // ws (40 MB): Wqt@0(2M) | Wkvt@2M(4M) | Wpt@6M(2M) | Qb@8M(16M, becomes O) |
  //   Vtb@24M(16M).
  // d_out (32 MiB) scratch before final overwrite: Kb@0 (16MiB bf16 K),
  // Xb@16MiB (16MiB bf16 xo).
  char* ws = (char*)d_ws;
  u16* Wqt  = (u16*)(ws + ((size_t)0 << 20));
  u16* Wkvt = (u16*)(ws + ((size_t)2 << 20));
  u16* Wpt  = (u16*)(ws + ((size_t)6 << 20));
  u16* Qb   = (u16*)(ws + ((size_t)8 << 20));
  u16* Vtb  = (u16*)(ws + ((size_t)24 << 20));
  u16* Kb   = (u16*)d_out;
  u16* Xb   = (u16*)((char*)d_out + ((size_t)16 << 20));

  const dim3 blk(256);
  prep_all<<<dim3(8192), blk, 0, stream>>>(
      Wq, Wk, Wv, Wp, Wqt, Wkvt, Wkvt + 1024 * 1024, Wpt, xo, Xb);

  gemm_fused<<<dim3(64, 24), blk, 0, stream>>>(x, Xb, Wqt, Wkvt, Qb, Kb, Vtb);

  attn_kernel<<<dim3(512), dim3(512), 0, stream>>>(Qb, Kb, Vtb, dec, Qb);

  gemm_out<<<dim3(64, 8), blk, 0, stream>>>(Qb, Wpt, out);
}